// Round 3
// baseline (1852.588 us; speedup 1.0000x reference)
//
#include <hip/hip_runtime.h>

// Linear SSM group scan: chunk-4 parallel phases + 2-level inter-chunk scan.
// G=2, B=128, L=2048, SD=64, ID=16, OD=16. All fp32, exact decomposition.
//
// R3: (a) __launch_bounds__(256,4) on kA/kC (R2 ran at ~2 blocks/CU; LDS 20KB
//     and VGPR 100 permit 4+) to hide s_load/lgkm latency across waves;
//     (b) inner products as inline-asm v_pk_fma_f32 (VOP3P) with the matrix
//     pair in SGPR (src0) and state pair in VGPR - halves VALU issue vs the
//     scalarized 2x v_fma_f32 hipcc emitted from v2 arithmetic;
//     (c) kC barriers 3->2 per step (prev barrier C already orders zb reads
//     before next zb write; barrier B orders ob readers before next ob write).
// kB0/kB1/kB2 unchanged.
#define G_ 2
#define B_ 128
#define L_ 2048
#define SD 64
#define ID 16
#define OD 16
#define NC4 512
#define NC8 256
#define OBS_BASE ((size_t)(G_) * B_ * L_ * SD)

typedef float v2 __attribute__((ext_vector_type(2)));

static __device__ __forceinline__ size_t slotof(int g, int b, int l) {
  return (((size_t)g * B_ + b) * L_ + l) * (size_t)SD;
}
static __device__ __forceinline__ float rl(float v, int lane) {
  return __builtin_bit_cast(float, __builtin_amdgcn_readlane(__builtin_bit_cast(int, v), lane));
}
// acc += m * z, packed fp32; m is wave-uniform (SGPR pair), z per-lane.
static __device__ __forceinline__ void pkfma_s(v2& acc, v2 m, v2 z) {
  asm("v_pk_fma_f32 %0, %1, %2, %0" : "+v"(acc) : "s"(m), "v"(z));
}

// C = A*A (64x64), 256 threads. Caller syncs before and after.
static __device__ void lds_sq(const float* A, float* C, int tid) {
  const int r = tid & 63, q = tid >> 6;
  const float4* Ar = (const float4*)(A + r * SD);
  float acc[16];
#pragma unroll
  for (int c = 0; c < 16; ++c) acc[c] = 0.f;
#pragma unroll 1
  for (int k4 = 0; k4 < 16; ++k4) {
    float4 af = Ar[k4];
    const float* Bb = A + k4 * 4 * SD + q * 16;
#pragma unroll
    for (int kk = 0; kk < 4; ++kk) {
      float a = (kk == 0) ? af.x : (kk == 1) ? af.y : (kk == 2) ? af.z : af.w;
      const float4* Bk = (const float4*)(Bb + kk * SD);
#pragma unroll
      for (int c = 0; c < 4; ++c) {
        float4 bv = Bk[c];
        acc[4 * c + 0] = fmaf(a, bv.x, acc[4 * c + 0]);
        acc[4 * c + 1] = fmaf(a, bv.y, acc[4 * c + 1]);
        acc[4 * c + 2] = fmaf(a, bv.z, acc[4 * c + 2]);
        acc[4 * c + 3] = fmaf(a, bv.w, acc[4 * c + 3]);
      }
    }
  }
  float4* Cr = (float4*)(C + r * SD + q * 16);
#pragma unroll
  for (int c = 0; c < 4; ++c)
    Cr[c] = make_float4(acc[4 * c], acc[4 * c + 1], acc[4 * c + 2], acc[4 * c + 3]);
}

// ---------------------------------------------------------------------------
// kA: zero-init chunk-4 recurrence (fused noise coloring + input drive).
// Writes ONLY zend4 = slot l0+3. Matrices via scalar path (uniform idx).
// ---------------------------------------------------------------------------
__global__ __launch_bounds__(256, 4) void kA(
    const float* __restrict__ wn, const float* __restrict__ inp,
    const float* __restrict__ Fm, const float* __restrict__ Bm,
    const float* __restrict__ SW, float* __restrict__ out) {
  __shared__ __align__(16) float zb[SD * 64];   // 16 KB [comp][item]
  const int tid = threadIdx.x;
  const int bid = (int)blockIdx.x;
  const int c4 = bid & (NC4 - 1);
  const int half = (bid >> 9) & 1;
  const int g = bid >> 10;               // uniform (blockIdx)
  const int l0 = c4 * 4;
  const int lane = tid & 63;
  const int ww = __builtin_amdgcn_readfirstlane(tid >> 6);  // uniform wave id
  const int b = half * 64 + lane;
  const int row0 = ww * 16;              // uniform
  const float* __restrict__ Fg = Fm + g * SD * SD;
  const float* __restrict__ Wg = SW + g * SD * SD;
  const float* __restrict__ Bg = Bm + g * SD * ID;

  v2 z2[32];
#pragma unroll
  for (int k = 0; k < 32; ++k) z2[k] = (v2){0.f, 0.f};

#pragma unroll 1
  for (int j = 0; j < 4; ++j) {
    const int l = l0 + j;
    v2 w2[32];
    const v2* wp = (const v2*)(wn + (((size_t)l * G_ + g) * B_ + b) * SD);
#pragma unroll
    for (int q = 0; q < 32; ++q) w2[q] = wp[q];
    v2 u2[8];
    const v2* up = (const v2*)(inp + (((size_t)g * B_ + b) * L_ + l) * ID);
#pragma unroll
    for (int q = 0; q < 8; ++q) u2[q] = up[q];
    __syncthreads();  // A: prev-step zb reads drained (no-op at j==0)
#pragma unroll 1
    for (int c = 0; c < 16; ++c) {
      const int row = row0 + c;  // uniform
      const v2* fr = (const v2*)(Fg + row * SD);
      const v2* sr = (const v2*)(Wg + row * SD);
      const v2* br = (const v2*)(Bg + row * ID);
      v2 a0 = {0.f, 0.f}, a1 = {0.f, 0.f}, a2 = {0.f, 0.f}, a3 = {0.f, 0.f};
#pragma unroll
      for (int q = 0; q < 16; ++q) {
        pkfma_s(a0, fr[2 * q + 0], z2[2 * q + 0]);
        pkfma_s(a1, fr[2 * q + 1], z2[2 * q + 1]);
        pkfma_s(a2, sr[2 * q + 0], w2[2 * q + 0]);
        pkfma_s(a3, sr[2 * q + 1], w2[2 * q + 1]);
      }
#pragma unroll
      for (int q = 0; q < 8; ++q) pkfma_s(a2, br[q], u2[q]);
      v2 aa = (a0 + a1) + (a2 + a3);
      zb[row * 64 + lane] = aa.x + aa.y;
    }
    __syncthreads();  // B: zb complete
    if (j != 3) {
#pragma unroll
      for (int k = 0; k < 32; ++k)
        z2[k] = (v2){zb[(2 * k) * 64 + lane], zb[(2 * k + 1) * 64 + lane]};
    }
  }
  // cooperative zend4 store: thread (item, kg) -> comps [16kg,16kg+16)
  {
    const int item = tid & 63;
    const int kg = tid >> 6;
    float* dst = out + slotof(g, half * 64 + item, l0 + 3);
#pragma unroll
    for (int r = 0; r < 4; ++r) {
      float4 v;
      v.x = zb[(kg * 16 + 4 * r + 0) * 64 + item];
      v.y = zb[(kg * 16 + 4 * r + 1) * 64 + item];
      v.z = zb[(kg * 16 + 4 * r + 2) * 64 + item];
      v.w = zb[(kg * 16 + 4 * r + 3) * 64 + item];
      ((float4*)dst)[kg * 4 + r] = v;
    }
  }
}

// ---------------------------------------------------------------------------
// kB0: d(c8) = F^4 * zend4(2c8) + zend4(2c8+1)  -> slot c8*8+0   (unchanged)
// ---------------------------------------------------------------------------
__global__ __launch_bounds__(256) void kB0(const float* __restrict__ Fm,
                                           float* __restrict__ out) {
  __shared__ __align__(16) float bufA[SD * SD];
  __shared__ __align__(16) float bufB[SD * SD];
  const int tid = threadIdx.x;
  const int idx = (int)blockIdx.x * 256 + tid;
  const int b = idx & 127;
  const int rest = idx >> 7;
  const int c8 = rest & (NC8 - 1);
  const int g = rest >> 8;
  {
    const float4* Fg = (const float4*)(Fm + g * SD * SD);
    float4* A4 = (float4*)bufA;
    for (int i = tid; i < SD * SD / 4; i += 256) A4[i] = Fg[i];
  }
  __syncthreads();
  lds_sq(bufA, bufB, tid);  __syncthreads();  // F^2
  lds_sq(bufB, bufA, tid);  __syncthreads();  // F^4 in bufA

  const float* za_p = out + slotof(g, b, c8 * 8 + 3);
  const float* zb_p = out + slotof(g, b, c8 * 8 + 7);
  float* d_p = out + slotof(g, b, c8 * 8);
  v2 x2[32];
  {
    const float4* xp = (const float4*)za_p;
#pragma unroll
    for (int q = 0; q < 16; ++q) {
      float4 f = xp[q];
      x2[2 * q] = (v2){f.x, f.y};
      x2[2 * q + 1] = (v2){f.z, f.w};
    }
  }
#pragma unroll 1
  for (int tg = 0; tg < 16; ++tg) {
    float4 zb4 = ((const float4*)zb_p)[tg];
    float zn[4];
#pragma unroll
    for (int i = 0; i < 4; ++i) {
      const float4* fr = (const float4*)(bufA + (tg * 4 + i) * SD);
      v2 acc = {0.f, 0.f};
#pragma unroll
      for (int q = 0; q < 16; ++q) {
        float4 f = fr[q];
        acc += (v2){f.x, f.y} * x2[2 * q] + (v2){f.z, f.w} * x2[2 * q + 1];
      }
      zn[i] = acc.x + acc.y + ((i == 0) ? zb4.x : (i == 1) ? zb4.y : (i == 2) ? zb4.z : zb4.w);
    }
    ((float4*)d_p)[tg] = make_float4(zn[0], zn[1], zn[2], zn[3]);
  }
}

// ---------------------------------------------------------------------------
// kB1: sequential chunk-8 scan. init8(c8+1) = F^8*init8(c8) + d(c8). (unchanged)
// ---------------------------------------------------------------------------
__global__ __launch_bounds__(256) void kB1(const float* __restrict__ Fm,
                                           const float* __restrict__ s0,
                                           float* __restrict__ out) {
  __shared__ __align__(16) float bufA[SD * SD];
  __shared__ __align__(16) float bufB[SD * SD];
  const int tid = threadIdx.x;
  const int gb = (int)blockIdx.x * 4 + (tid >> 6);
  const int g = gb >> 7, b = gb & 127;
  const int lane = tid & 63;
  {
    const int gg = ((int)blockIdx.x * 4) >> 7;  // uniform per block
    const float4* Fg = (const float4*)(Fm + gg * SD * SD);
    float4* A4 = (float4*)bufA;
    for (int i = tid; i < SD * SD / 4; i += 256) A4[i] = Fg[i];
  }
  __syncthreads();
  lds_sq(bufA, bufB, tid);  __syncthreads();  // F^2
  lds_sq(bufB, bufA, tid);  __syncthreads();  // F^4
  lds_sq(bufA, bufB, tid);  __syncthreads();  // F^8 in bufB

  float frow[SD];
  const float4* Fr = (const float4*)(bufB + lane * SD);
#pragma unroll
  for (int i = 0; i < 16; ++i) {
    float4 f = Fr[i];
    frow[4 * i] = f.x; frow[4 * i + 1] = f.y; frow[4 * i + 2] = f.z; frow[4 * i + 3] = f.w;
  }
  float s = s0[(g * B_ + b) * SD + lane];
  float dcur = out[slotof(g, b, 0) + lane];
  float dnext = out[slotof(g, b, 8) + lane];
#pragma unroll 1
  for (int c8 = 0; c8 < NC8; ++c8) {
    asm volatile("s_waitcnt vmcnt(0)" ::: "memory");  // dcur/dnext/dpf resident
    out[slotof(g, b, c8 * 8) + lane] = s;             // init8(c8); d(c8) already in regs
    const int cn = (c8 + 2 < NC8) ? c8 + 2 : NC8 - 1;
    float dpf = out[slotof(g, b, cn * 8) + lane];
    float a0 = dcur, a1 = 0.f, a2 = 0.f, a3 = 0.f;
#pragma unroll
    for (int k = 0; k < SD; k += 4) {
      a0 = fmaf(frow[k + 0], rl(s, k + 0), a0);
      a1 = fmaf(frow[k + 1], rl(s, k + 1), a1);
      a2 = fmaf(frow[k + 2], rl(s, k + 2), a2);
      a3 = fmaf(frow[k + 3], rl(s, k + 3), a3);
    }
    s = (a0 + a1) + (a2 + a3);
    dcur = dnext;
    dnext = dpf;
  }
}

// ---------------------------------------------------------------------------
// kB2: odd chunk-4 inits: init4(2c8+1) = F^4*init8(c8) + zend4(2c8). (unchanged)
// ---------------------------------------------------------------------------
__global__ __launch_bounds__(256) void kB2(const float* __restrict__ Fm,
                                           float* __restrict__ out) {
  __shared__ __align__(16) float bufA[SD * SD];
  __shared__ __align__(16) float bufB[SD * SD];
  const int tid = threadIdx.x;
  const int idx = (int)blockIdx.x * 256 + tid;
  const int b = idx & 127;
  const int rest = idx >> 7;
  const int c8 = rest & (NC8 - 1);
  const int g = rest >> 8;
  {
    const float4* Fg = (const float4*)(Fm + g * SD * SD);
    float4* A4 = (float4*)bufA;
    for (int i = tid; i < SD * SD / 4; i += 256) A4[i] = Fg[i];
  }
  __syncthreads();
  lds_sq(bufA, bufB, tid);  __syncthreads();
  lds_sq(bufB, bufA, tid);  __syncthreads();  // F^4 in bufA

  const float* x_p = out + slotof(g, b, c8 * 8);       // init8(c8)
  const float* zb_p = out + slotof(g, b, c8 * 8 + 3);  // zend4(2c8)
  float* o_p = out + slotof(g, b, c8 * 8 + 4);
  v2 x2[32];
  {
    const float4* xp = (const float4*)x_p;
#pragma unroll
    for (int q = 0; q < 16; ++q) {
      float4 f = xp[q];
      x2[2 * q] = (v2){f.x, f.y};
      x2[2 * q + 1] = (v2){f.z, f.w};
    }
  }
#pragma unroll 1
  for (int tg = 0; tg < 16; ++tg) {
    float4 zb4 = ((const float4*)zb_p)[tg];
    float zn[4];
#pragma unroll
    for (int i = 0; i < 4; ++i) {
      const float4* fr = (const float4*)(bufA + (tg * 4 + i) * SD);
      v2 acc = {0.f, 0.f};
#pragma unroll
      for (int q = 0; q < 16; ++q) {
        float4 f = fr[q];
        acc += (v2){f.x, f.y} * x2[2 * q] + (v2){f.z, f.w} * x2[2 * q + 1];
      }
      zn[i] = acc.x + acc.y + ((i == 0) ? zb4.x : (i == 1) ? zb4.y : (i == 2) ? zb4.z : zb4.w);
    }
    ((float4*)o_p)[tg] = make_float4(zn[0], zn[1], zn[2], zn[3]);
  }
}

// ---------------------------------------------------------------------------
// kC: true chunk-4 recurrence from init (slot l0), wave-per-component-range,
// matrices via scalar path + pk_fma; state regathered through zb; fused obs.
// 2 barriers per step.
// ---------------------------------------------------------------------------
__global__ __launch_bounds__(256, 4) void kC(
    const float* __restrict__ wn, const float* __restrict__ inp,
    const float* __restrict__ vn, const float* __restrict__ Fm,
    const float* __restrict__ Bm, const float* __restrict__ Hm,
    const float* __restrict__ SW, const float* __restrict__ SV,
    float* __restrict__ out) {
  __shared__ __align__(16) float zb[SD * 64];   // 16 KB [comp][item]
  __shared__ __align__(16) float ob[OD * 64];   // 4 KB  [oc][item]
  const int tid = threadIdx.x;
  const int bid = (int)blockIdx.x;
  const int c4 = bid & (NC4 - 1);
  const int half = (bid >> 9) & 1;
  const int g = bid >> 10;               // uniform
  const int l0 = c4 * 4;
  const int lane = tid & 63;
  const int ww = __builtin_amdgcn_readfirstlane(tid >> 6);  // uniform wave id
  const int b = half * 64 + lane;
  const int row0 = ww * 16;              // uniform
  const int item = tid & 63;             // cooperative-store role
  const int kg = tid >> 6;
  const float* __restrict__ Fg = Fm + g * SD * SD;
  const float* __restrict__ Wg = SW + g * SD * SD;
  const float* __restrict__ Bg = Bm + g * SD * ID;
  const float* __restrict__ Hg = Hm + g * OD * SD;
  const float* __restrict__ Vg = SV + g * OD * OD;

  v2 z2[32];
  {
    // init4(c4): per-lane contiguous load from slot l0 (written by kB1/kB2)
    const float4* ip = (const float4*)(out + slotof(g, b, l0));
#pragma unroll
    for (int q = 0; q < 16; ++q) {
      float4 f = ip[q];
      z2[2 * q] = (v2){f.x, f.y};
      z2[2 * q + 1] = (v2){f.z, f.w};
    }
  }
#pragma unroll 1
  for (int j = 0; j < 4; ++j) {
    const int l = l0 + j;
    v2 w2[32];
    const v2* wp = (const v2*)(wn + (((size_t)l * G_ + g) * B_ + b) * SD);
#pragma unroll
    for (int q = 0; q < 32; ++q) w2[q] = wp[q];
    v2 u2[8];
    const v2* up = (const v2*)(inp + (((size_t)g * B_ + b) * L_ + l) * ID);
#pragma unroll
    for (int q = 0; q < 8; ++q) u2[q] = up[q];
    v2 vv2[8];
    const v2* vp = (const v2*)(vn + (((size_t)l * G_ + g) * B_ + b) * OD);
#pragma unroll
    for (int q = 0; q < 8; ++q) vv2[q] = vp[q];

    // zb writes: prior readers drained by barrier C of previous iteration.
#pragma unroll 1
    for (int c = 0; c < 16; ++c) {
      const int row = row0 + c;  // uniform
      const v2* fr = (const v2*)(Fg + row * SD);
      const v2* sr = (const v2*)(Wg + row * SD);
      const v2* br = (const v2*)(Bg + row * ID);
      v2 a0 = {0.f, 0.f}, a1 = {0.f, 0.f}, a2 = {0.f, 0.f}, a3 = {0.f, 0.f};
#pragma unroll
      for (int q = 0; q < 16; ++q) {
        pkfma_s(a0, fr[2 * q + 0], z2[2 * q + 0]);
        pkfma_s(a1, fr[2 * q + 1], z2[2 * q + 1]);
        pkfma_s(a2, sr[2 * q + 0], w2[2 * q + 0]);
        pkfma_s(a3, sr[2 * q + 1], w2[2 * q + 1]);
      }
#pragma unroll
      for (int q = 0; q < 8; ++q) pkfma_s(a2, br[q], u2[q]);
      v2 aa = (a0 + a1) + (a2 + a3);
      zb[row * 64 + lane] = aa.x + aa.y;
    }
    __syncthreads();  // B: zb = state(l) complete (also orders prev ob reads
                      // before this step's ob writes below)
    // cooperative state store
    {
      float* dst = out + slotof(g, half * 64 + item, l);
#pragma unroll
      for (int r = 0; r < 4; ++r) {
        float4 v;
        v.x = zb[(kg * 16 + 4 * r + 0) * 64 + item];
        v.y = zb[(kg * 16 + 4 * r + 1) * 64 + item];
        v.z = zb[(kg * 16 + 4 * r + 2) * 64 + item];
        v.w = zb[(kg * 16 + 4 * r + 3) * 64 + item];
        ((float4*)dst)[kg * 4 + r] = v;
      }
    }
    // regather full state(l) into regs (also feeds next step)
#pragma unroll
    for (int k = 0; k < 32; ++k)
      z2[k] = (v2){zb[(2 * k) * 64 + lane], zb[(2 * k + 1) * 64 + lane]};
    // observations: wave ww computes obs rows [4ww, 4ww+4)
#pragma unroll
    for (int oc = 0; oc < 4; ++oc) {
      const int orow = ww * 4 + oc;  // uniform
      const v2* hr = (const v2*)(Hg + orow * SD);
      const v2* vr = (const v2*)(Vg + orow * OD);
      v2 a0 = {0.f, 0.f}, a1 = {0.f, 0.f};
#pragma unroll
      for (int q = 0; q < 16; ++q) {
        pkfma_s(a0, hr[2 * q + 0], z2[2 * q + 0]);
        pkfma_s(a1, hr[2 * q + 1], z2[2 * q + 1]);
      }
#pragma unroll
      for (int q = 0; q < 8; ++q) pkfma_s(a0, vr[q], vv2[q]);
      v2 aa = a0 + a1;
      ob[orow * 64 + lane] = aa.x + aa.y;
    }
    __syncthreads();  // C: ob complete (also orders zb reads before next write)
    // cooperative obs store: thread (item, kg) stores float4 #kg
    {
      float4 v;
      v.x = ob[(4 * kg + 0) * 64 + item];
      v.y = ob[(4 * kg + 1) * 64 + item];
      v.z = ob[(4 * kg + 2) * 64 + item];
      v.w = ob[(4 * kg + 3) * 64 + item];
      float* od = out + OBS_BASE +
                  (((size_t)g * B_ + (half * 64 + item)) * L_ + l) * OD;
      ((float4*)od)[kg] = v;
    }
  }
}

extern "C" void kernel_launch(void* const* d_in, const int* in_sizes, int n_in,
                              void* d_out, int out_size, void* d_ws, size_t ws_size,
                              hipStream_t stream) {
  (void)in_sizes; (void)n_in; (void)out_size; (void)d_ws; (void)ws_size;
  const float* state0 = (const float*)d_in[0];
  const float* inputs = (const float*)d_in[1];
  const float* Fm     = (const float*)d_in[2];
  const float* Bm     = (const float*)d_in[3];
  const float* Hm     = (const float*)d_in[4];
  const float* SW     = (const float*)d_in[5];
  const float* SV     = (const float*)d_in[6];
  const float* wn     = (const float*)d_in[7];
  const float* vn     = (const float*)d_in[8];
  float* out = (float*)d_out;

  kA<<<2048, 256, 0, stream>>>(wn, inputs, Fm, Bm, SW, out);
  kB0<<<256, 256, 0, stream>>>(Fm, out);
  kB1<<<64, 256, 0, stream>>>(Fm, state0, out);
  kB2<<<256, 256, 0, stream>>>(Fm, out);
  kC<<<2048, 256, 0, stream>>>(wn, inputs, vn, Fm, Bm, Hm, SW, SV, out);
}

// Round 4
// 1186.956 us; speedup vs baseline: 1.5608x; 1.5608x over previous
//
#include <hip/hip_runtime.h>

// Linear SSM group scan: chunk-4 parallel phases + 2-level inter-chunk scan.
// G=2, B=128, L=2048, SD=64, ID=16, OD=16. All fp32, exact decomposition.
//
// R4: - revert launch_bounds to (256,2): R3's (256,4) forced VGPR=64 -> spill
//       (FETCH 121->917 MB was scratch traffic). pk_fma itself halved VALU
//       busy (133->83 us) so it stays.
//     - lgkm-only raw barriers (asm s_waitcnt lgkmcnt(0); s_barrier): the
//       block's barriers only order LDS (zb/ob); __syncthreads' implicit
//       vmcnt(0) drain was killing cross-barrier load pipelining.
//     - software-pipelined next-step w/u/v loads: issued right after the row
//       loop (regs dead there), consumed next iteration; they stay in flight
//       across barrier + state store + regather + obs. j-loop fully unrolled
//       so SSA renaming avoids register copies.
// kB0/kB1/kB2 unchanged.
#define G_ 2
#define B_ 128
#define L_ 2048
#define SD 64
#define ID 16
#define OD 16
#define NC4 512
#define NC8 256
#define OBS_BASE ((size_t)(G_) * B_ * L_ * SD)

typedef float v2 __attribute__((ext_vector_type(2)));

static __device__ __forceinline__ size_t slotof(int g, int b, int l) {
  return (((size_t)g * B_ + b) * L_ + l) * (size_t)SD;
}
static __device__ __forceinline__ float rl(float v, int lane) {
  return __builtin_bit_cast(float, __builtin_amdgcn_readlane(__builtin_bit_cast(int, v), lane));
}
// acc += m * z, packed fp32; m is wave-uniform (SGPR pair), z per-lane.
static __device__ __forceinline__ void pkfma_s(v2& acc, v2 m, v2 z) {
  asm("v_pk_fma_f32 %0, %1, %2, %0" : "+v"(acc) : "s"(m), "v"(z));
}
// LDS-only barrier: order ds ops without draining vmcnt (no global op inside
// the block's barrier protocol needs cross-thread visibility).
static __device__ __forceinline__ void lds_barrier() {
  asm volatile("s_waitcnt lgkmcnt(0)\n\ts_barrier" ::: "memory");
}

// C = A*A (64x64), 256 threads. Caller syncs before and after.
static __device__ void lds_sq(const float* A, float* C, int tid) {
  const int r = tid & 63, q = tid >> 6;
  const float4* Ar = (const float4*)(A + r * SD);
  float acc[16];
#pragma unroll
  for (int c = 0; c < 16; ++c) acc[c] = 0.f;
#pragma unroll 1
  for (int k4 = 0; k4 < 16; ++k4) {
    float4 af = Ar[k4];
    const float* Bb = A + k4 * 4 * SD + q * 16;
#pragma unroll
    for (int kk = 0; kk < 4; ++kk) {
      float a = (kk == 0) ? af.x : (kk == 1) ? af.y : (kk == 2) ? af.z : af.w;
      const float4* Bk = (const float4*)(Bb + kk * SD);
#pragma unroll
      for (int c = 0; c < 4; ++c) {
        float4 bv = Bk[c];
        acc[4 * c + 0] = fmaf(a, bv.x, acc[4 * c + 0]);
        acc[4 * c + 1] = fmaf(a, bv.y, acc[4 * c + 1]);
        acc[4 * c + 2] = fmaf(a, bv.z, acc[4 * c + 2]);
        acc[4 * c + 3] = fmaf(a, bv.w, acc[4 * c + 3]);
      }
    }
  }
  float4* Cr = (float4*)(C + r * SD + q * 16);
#pragma unroll
  for (int c = 0; c < 4; ++c)
    Cr[c] = make_float4(acc[4 * c], acc[4 * c + 1], acc[4 * c + 2], acc[4 * c + 3]);
}

// ---------------------------------------------------------------------------
// kA: zero-init chunk-4 recurrence (fused noise coloring + input drive).
// Writes ONLY zend4 = slot l0+3. Matrices via scalar path (uniform idx).
// ---------------------------------------------------------------------------
__global__ __launch_bounds__(256, 2) void kA(
    const float* __restrict__ wn, const float* __restrict__ inp,
    const float* __restrict__ Fm, const float* __restrict__ Bm,
    const float* __restrict__ SW, float* __restrict__ out) {
  __shared__ __align__(16) float zb[SD * 64];   // 16 KB [comp][item]
  const int tid = threadIdx.x;
  const int bid = (int)blockIdx.x;
  const int c4 = bid & (NC4 - 1);
  const int half = (bid >> 9) & 1;
  const int g = bid >> 10;               // uniform (blockIdx)
  const int l0 = c4 * 4;
  const int lane = tid & 63;
  const int ww = __builtin_amdgcn_readfirstlane(tid >> 6);  // uniform wave id
  const int b = half * 64 + lane;
  const int row0 = ww * 16;              // uniform
  const float* __restrict__ Fg = Fm + g * SD * SD;
  const float* __restrict__ Wg = SW + g * SD * SD;
  const float* __restrict__ Bg = Bm + g * SD * ID;

  v2 z2[32];
#pragma unroll
  for (int k = 0; k < 32; ++k) z2[k] = (v2){0.f, 0.f};

  // preload step-0 noise/input
  v2 w2[32], u2[8];
  {
    const v2* wp = (const v2*)(wn + (((size_t)l0 * G_ + g) * B_ + b) * SD);
#pragma unroll
    for (int q = 0; q < 32; ++q) w2[q] = wp[q];
    const v2* up = (const v2*)(inp + (((size_t)g * B_ + b) * L_ + l0) * ID);
#pragma unroll
    for (int q = 0; q < 8; ++q) u2[q] = up[q];
  }

#pragma unroll
  for (int j = 0; j < 4; ++j) {
    if (j) lds_barrier();  // A: prev-step zb reads drained
#pragma unroll 1
    for (int c = 0; c < 16; ++c) {
      const int row = row0 + c;  // uniform
      const v2* fr = (const v2*)(Fg + row * SD);
      const v2* sr = (const v2*)(Wg + row * SD);
      const v2* br = (const v2*)(Bg + row * ID);
      v2 a0 = {0.f, 0.f}, a1 = {0.f, 0.f}, a2 = {0.f, 0.f}, a3 = {0.f, 0.f};
#pragma unroll
      for (int q = 0; q < 16; ++q) {
        pkfma_s(a0, fr[2 * q + 0], z2[2 * q + 0]);
        pkfma_s(a1, fr[2 * q + 1], z2[2 * q + 1]);
        pkfma_s(a2, sr[2 * q + 0], w2[2 * q + 0]);
        pkfma_s(a3, sr[2 * q + 1], w2[2 * q + 1]);
      }
#pragma unroll
      for (int q = 0; q < 8; ++q) pkfma_s(a2, br[q], u2[q]);
      v2 aa = (a0 + a1) + (a2 + a3);
      zb[row * 64 + lane] = aa.x + aa.y;
    }
    // prefetch next-step noise/input: in flight across barrier B + regather
    if (j != 3) {
      const int ln = l0 + j + 1;
      const v2* wp = (const v2*)(wn + (((size_t)ln * G_ + g) * B_ + b) * SD);
#pragma unroll
      for (int q = 0; q < 32; ++q) w2[q] = wp[q];
      const v2* up = (const v2*)(inp + (((size_t)g * B_ + b) * L_ + ln) * ID);
#pragma unroll
      for (int q = 0; q < 8; ++q) u2[q] = up[q];
    }
    lds_barrier();  // B: zb complete
    if (j != 3) {
#pragma unroll
      for (int k = 0; k < 32; ++k)
        z2[k] = (v2){zb[(2 * k) * 64 + lane], zb[(2 * k + 1) * 64 + lane]};
    }
  }
  // cooperative zend4 store: thread (item, kg) -> comps [16kg,16kg+16)
  {
    const int item = tid & 63;
    const int kg = tid >> 6;
    float* dst = out + slotof(g, half * 64 + item, l0 + 3);
#pragma unroll
    for (int r = 0; r < 4; ++r) {
      float4 v;
      v.x = zb[(kg * 16 + 4 * r + 0) * 64 + item];
      v.y = zb[(kg * 16 + 4 * r + 1) * 64 + item];
      v.z = zb[(kg * 16 + 4 * r + 2) * 64 + item];
      v.w = zb[(kg * 16 + 4 * r + 3) * 64 + item];
      ((float4*)dst)[kg * 4 + r] = v;
    }
  }
}

// ---------------------------------------------------------------------------
// kB0: d(c8) = F^4 * zend4(2c8) + zend4(2c8+1)  -> slot c8*8+0   (unchanged)
// ---------------------------------------------------------------------------
__global__ __launch_bounds__(256) void kB0(const float* __restrict__ Fm,
                                           float* __restrict__ out) {
  __shared__ __align__(16) float bufA[SD * SD];
  __shared__ __align__(16) float bufB[SD * SD];
  const int tid = threadIdx.x;
  const int idx = (int)blockIdx.x * 256 + tid;
  const int b = idx & 127;
  const int rest = idx >> 7;
  const int c8 = rest & (NC8 - 1);
  const int g = rest >> 8;
  {
    const float4* Fg = (const float4*)(Fm + g * SD * SD);
    float4* A4 = (float4*)bufA;
    for (int i = tid; i < SD * SD / 4; i += 256) A4[i] = Fg[i];
  }
  __syncthreads();
  lds_sq(bufA, bufB, tid);  __syncthreads();  // F^2
  lds_sq(bufB, bufA, tid);  __syncthreads();  // F^4 in bufA

  const float* za_p = out + slotof(g, b, c8 * 8 + 3);
  const float* zb_p = out + slotof(g, b, c8 * 8 + 7);
  float* d_p = out + slotof(g, b, c8 * 8);
  v2 x2[32];
  {
    const float4* xp = (const float4*)za_p;
#pragma unroll
    for (int q = 0; q < 16; ++q) {
      float4 f = xp[q];
      x2[2 * q] = (v2){f.x, f.y};
      x2[2 * q + 1] = (v2){f.z, f.w};
    }
  }
#pragma unroll 1
  for (int tg = 0; tg < 16; ++tg) {
    float4 zb4 = ((const float4*)zb_p)[tg];
    float zn[4];
#pragma unroll
    for (int i = 0; i < 4; ++i) {
      const float4* fr = (const float4*)(bufA + (tg * 4 + i) * SD);
      v2 acc = {0.f, 0.f};
#pragma unroll
      for (int q = 0; q < 16; ++q) {
        float4 f = fr[q];
        acc += (v2){f.x, f.y} * x2[2 * q] + (v2){f.z, f.w} * x2[2 * q + 1];
      }
      zn[i] = acc.x + acc.y + ((i == 0) ? zb4.x : (i == 1) ? zb4.y : (i == 2) ? zb4.z : zb4.w);
    }
    ((float4*)d_p)[tg] = make_float4(zn[0], zn[1], zn[2], zn[3]);
  }
}

// ---------------------------------------------------------------------------
// kB1: sequential chunk-8 scan. init8(c8+1) = F^8*init8(c8) + d(c8). (unchanged)
// ---------------------------------------------------------------------------
__global__ __launch_bounds__(256) void kB1(const float* __restrict__ Fm,
                                           const float* __restrict__ s0,
                                           float* __restrict__ out) {
  __shared__ __align__(16) float bufA[SD * SD];
  __shared__ __align__(16) float bufB[SD * SD];
  const int tid = threadIdx.x;
  const int gb = (int)blockIdx.x * 4 + (tid >> 6);
  const int g = gb >> 7, b = gb & 127;
  const int lane = tid & 63;
  {
    const int gg = ((int)blockIdx.x * 4) >> 7;  // uniform per block
    const float4* Fg = (const float4*)(Fm + gg * SD * SD);
    float4* A4 = (float4*)bufA;
    for (int i = tid; i < SD * SD / 4; i += 256) A4[i] = Fg[i];
  }
  __syncthreads();
  lds_sq(bufA, bufB, tid);  __syncthreads();  // F^2
  lds_sq(bufB, bufA, tid);  __syncthreads();  // F^4
  lds_sq(bufA, bufB, tid);  __syncthreads();  // F^8 in bufB

  float frow[SD];
  const float4* Fr = (const float4*)(bufB + lane * SD);
#pragma unroll
  for (int i = 0; i < 16; ++i) {
    float4 f = Fr[i];
    frow[4 * i] = f.x; frow[4 * i + 1] = f.y; frow[4 * i + 2] = f.z; frow[4 * i + 3] = f.w;
  }
  float s = s0[(g * B_ + b) * SD + lane];
  float dcur = out[slotof(g, b, 0) + lane];
  float dnext = out[slotof(g, b, 8) + lane];
#pragma unroll 1
  for (int c8 = 0; c8 < NC8; ++c8) {
    asm volatile("s_waitcnt vmcnt(0)" ::: "memory");  // dcur/dnext/dpf resident
    out[slotof(g, b, c8 * 8) + lane] = s;             // init8(c8); d(c8) already in regs
    const int cn = (c8 + 2 < NC8) ? c8 + 2 : NC8 - 1;
    float dpf = out[slotof(g, b, cn * 8) + lane];
    float a0 = dcur, a1 = 0.f, a2 = 0.f, a3 = 0.f;
#pragma unroll
    for (int k = 0; k < SD; k += 4) {
      a0 = fmaf(frow[k + 0], rl(s, k + 0), a0);
      a1 = fmaf(frow[k + 1], rl(s, k + 1), a1);
      a2 = fmaf(frow[k + 2], rl(s, k + 2), a2);
      a3 = fmaf(frow[k + 3], rl(s, k + 3), a3);
    }
    s = (a0 + a1) + (a2 + a3);
    dcur = dnext;
    dnext = dpf;
  }
}

// ---------------------------------------------------------------------------
// kB2: odd chunk-4 inits: init4(2c8+1) = F^4*init8(c8) + zend4(2c8). (unchanged)
// ---------------------------------------------------------------------------
__global__ __launch_bounds__(256) void kB2(const float* __restrict__ Fm,
                                           float* __restrict__ out) {
  __shared__ __align__(16) float bufA[SD * SD];
  __shared__ __align__(16) float bufB[SD * SD];
  const int tid = threadIdx.x;
  const int idx = (int)blockIdx.x * 256 + tid;
  const int b = idx & 127;
  const int rest = idx >> 7;
  const int c8 = rest & (NC8 - 1);
  const int g = rest >> 8;
  {
    const float4* Fg = (const float4*)(Fm + g * SD * SD);
    float4* A4 = (float4*)bufA;
    for (int i = tid; i < SD * SD / 4; i += 256) A4[i] = Fg[i];
  }
  __syncthreads();
  lds_sq(bufA, bufB, tid);  __syncthreads();
  lds_sq(bufB, bufA, tid);  __syncthreads();  // F^4 in bufA

  const float* x_p = out + slotof(g, b, c8 * 8);       // init8(c8)
  const float* zb_p = out + slotof(g, b, c8 * 8 + 3);  // zend4(2c8)
  float* o_p = out + slotof(g, b, c8 * 8 + 4);
  v2 x2[32];
  {
    const float4* xp = (const float4*)x_p;
#pragma unroll
    for (int q = 0; q < 16; ++q) {
      float4 f = xp[q];
      x2[2 * q] = (v2){f.x, f.y};
      x2[2 * q + 1] = (v2){f.z, f.w};
    }
  }
#pragma unroll 1
  for (int tg = 0; tg < 16; ++tg) {
    float4 zb4 = ((const float4*)zb_p)[tg];
    float zn[4];
#pragma unroll
    for (int i = 0; i < 4; ++i) {
      const float4* fr = (const float4*)(bufA + (tg * 4 + i) * SD);
      v2 acc = {0.f, 0.f};
#pragma unroll
      for (int q = 0; q < 16; ++q) {
        float4 f = fr[q];
        acc += (v2){f.x, f.y} * x2[2 * q] + (v2){f.z, f.w} * x2[2 * q + 1];
      }
      zn[i] = acc.x + acc.y + ((i == 0) ? zb4.x : (i == 1) ? zb4.y : (i == 2) ? zb4.z : zb4.w);
    }
    ((float4*)o_p)[tg] = make_float4(zn[0], zn[1], zn[2], zn[3]);
  }
}

// ---------------------------------------------------------------------------
// kC: true chunk-4 recurrence from init (slot l0), wave-per-component-range,
// matrices via scalar path + pk_fma; state regathered through zb; fused obs.
// 2 lgkm-only barriers per step; next-step loads pipelined across barrier B.
// ---------------------------------------------------------------------------
__global__ __launch_bounds__(256, 2) void kC(
    const float* __restrict__ wn, const float* __restrict__ inp,
    const float* __restrict__ vn, const float* __restrict__ Fm,
    const float* __restrict__ Bm, const float* __restrict__ Hm,
    const float* __restrict__ SW, const float* __restrict__ SV,
    float* __restrict__ out) {
  __shared__ __align__(16) float zb[SD * 64];   // 16 KB [comp][item]
  __shared__ __align__(16) float ob[OD * 64];   // 4 KB  [oc][item]
  const int tid = threadIdx.x;
  const int bid = (int)blockIdx.x;
  const int c4 = bid & (NC4 - 1);
  const int half = (bid >> 9) & 1;
  const int g = bid >> 10;               // uniform
  const int l0 = c4 * 4;
  const int lane = tid & 63;
  const int ww = __builtin_amdgcn_readfirstlane(tid >> 6);  // uniform wave id
  const int b = half * 64 + lane;
  const int row0 = ww * 16;              // uniform
  const int item = tid & 63;             // cooperative-store role
  const int kg = tid >> 6;
  const float* __restrict__ Fg = Fm + g * SD * SD;
  const float* __restrict__ Wg = SW + g * SD * SD;
  const float* __restrict__ Bg = Bm + g * SD * ID;
  const float* __restrict__ Hg = Hm + g * OD * SD;
  const float* __restrict__ Vg = SV + g * OD * OD;

  v2 z2[32];
  {
    // init4(c4): per-lane contiguous load from slot l0 (written by kB1/kB2)
    const float4* ip = (const float4*)(out + slotof(g, b, l0));
#pragma unroll
    for (int q = 0; q < 16; ++q) {
      float4 f = ip[q];
      z2[2 * q] = (v2){f.x, f.y};
      z2[2 * q + 1] = (v2){f.z, f.w};
    }
  }
  // preload step-0 noise/input/obs-noise
  v2 w2[32], u2[8], vv2[8];
  {
    const v2* wp = (const v2*)(wn + (((size_t)l0 * G_ + g) * B_ + b) * SD);
#pragma unroll
    for (int q = 0; q < 32; ++q) w2[q] = wp[q];
    const v2* up = (const v2*)(inp + (((size_t)g * B_ + b) * L_ + l0) * ID);
#pragma unroll
    for (int q = 0; q < 8; ++q) u2[q] = up[q];
    const v2* vp = (const v2*)(vn + (((size_t)l0 * G_ + g) * B_ + b) * OD);
#pragma unroll
    for (int q = 0; q < 8; ++q) vv2[q] = vp[q];
  }

#pragma unroll
  for (int j = 0; j < 4; ++j) {
    const int l = l0 + j;
    // zb writes: prior readers drained by barrier C of previous iteration.
#pragma unroll 1
    for (int c = 0; c < 16; ++c) {
      const int row = row0 + c;  // uniform
      const v2* fr = (const v2*)(Fg + row * SD);
      const v2* sr = (const v2*)(Wg + row * SD);
      const v2* br = (const v2*)(Bg + row * ID);
      v2 a0 = {0.f, 0.f}, a1 = {0.f, 0.f}, a2 = {0.f, 0.f}, a3 = {0.f, 0.f};
#pragma unroll
      for (int q = 0; q < 16; ++q) {
        pkfma_s(a0, fr[2 * q + 0], z2[2 * q + 0]);
        pkfma_s(a1, fr[2 * q + 1], z2[2 * q + 1]);
        pkfma_s(a2, sr[2 * q + 0], w2[2 * q + 0]);
        pkfma_s(a3, sr[2 * q + 1], w2[2 * q + 1]);
      }
#pragma unroll
      for (int q = 0; q < 8; ++q) pkfma_s(a2, br[q], u2[q]);
      v2 aa = (a0 + a1) + (a2 + a3);
      zb[row * 64 + lane] = aa.x + aa.y;
    }
    // prefetch next-step w/u (w2/u2 dead now); in flight across barrier B,
    // state store, regather and obs. vv2 still live (obs below) -> vn2 sep.
    v2 vn2[8];
    if (j != 3) {
      const int ln = l + 1;
      const v2* wp = (const v2*)(wn + (((size_t)ln * G_ + g) * B_ + b) * SD);
#pragma unroll
      for (int q = 0; q < 32; ++q) w2[q] = wp[q];
      const v2* up = (const v2*)(inp + (((size_t)g * B_ + b) * L_ + ln) * ID);
#pragma unroll
      for (int q = 0; q < 8; ++q) u2[q] = up[q];
      const v2* vp = (const v2*)(vn + (((size_t)ln * G_ + g) * B_ + b) * OD);
#pragma unroll
      for (int q = 0; q < 8; ++q) vn2[q] = vp[q];
    }
    lds_barrier();  // B: zb = state(l) complete (also: prev ob reads done)
    // cooperative state store
    {
      float* dst = out + slotof(g, half * 64 + item, l);
#pragma unroll
      for (int r = 0; r < 4; ++r) {
        float4 v;
        v.x = zb[(kg * 16 + 4 * r + 0) * 64 + item];
        v.y = zb[(kg * 16 + 4 * r + 1) * 64 + item];
        v.z = zb[(kg * 16 + 4 * r + 2) * 64 + item];
        v.w = zb[(kg * 16 + 4 * r + 3) * 64 + item];
        ((float4*)dst)[kg * 4 + r] = v;
      }
    }
    // regather full state(l) into regs (also feeds next step)
#pragma unroll
    for (int k = 0; k < 32; ++k)
      z2[k] = (v2){zb[(2 * k) * 64 + lane], zb[(2 * k + 1) * 64 + lane]};
    // observations: wave ww computes obs rows [4ww, 4ww+4)
#pragma unroll
    for (int oc = 0; oc < 4; ++oc) {
      const int orow = ww * 4 + oc;  // uniform
      const v2* hr = (const v2*)(Hg + orow * SD);
      const v2* vr = (const v2*)(Vg + orow * OD);
      v2 a0 = {0.f, 0.f}, a1 = {0.f, 0.f};
#pragma unroll
      for (int q = 0; q < 16; ++q) {
        pkfma_s(a0, hr[2 * q + 0], z2[2 * q + 0]);
        pkfma_s(a1, hr[2 * q + 1], z2[2 * q + 1]);
      }
#pragma unroll
      for (int q = 0; q < 8; ++q) pkfma_s(a0, vr[q], vv2[q]);
      v2 aa = a0 + a1;
      ob[orow * 64 + lane] = aa.x + aa.y;
    }
    lds_barrier();  // C: ob complete (also orders zb reads before next write)
    // cooperative obs store: thread (item, kg) stores float4 #kg
    {
      float4 v;
      v.x = ob[(4 * kg + 0) * 64 + item];
      v.y = ob[(4 * kg + 1) * 64 + item];
      v.z = ob[(4 * kg + 2) * 64 + item];
      v.w = ob[(4 * kg + 3) * 64 + item];
      float* od = out + OBS_BASE +
                  (((size_t)g * B_ + (half * 64 + item)) * L_ + l) * OD;
      ((float4*)od)[kg] = v;
    }
    if (j != 3) {
#pragma unroll
      for (int q = 0; q < 8; ++q) vv2[q] = vn2[q];
    }
  }
}

extern "C" void kernel_launch(void* const* d_in, const int* in_sizes, int n_in,
                              void* d_out, int out_size, void* d_ws, size_t ws_size,
                              hipStream_t stream) {
  (void)in_sizes; (void)n_in; (void)out_size; (void)d_ws; (void)ws_size;
  const float* state0 = (const float*)d_in[0];
  const float* inputs = (const float*)d_in[1];
  const float* Fm     = (const float*)d_in[2];
  const float* Bm     = (const float*)d_in[3];
  const float* Hm     = (const float*)d_in[4];
  const float* SW     = (const float*)d_in[5];
  const float* SV     = (const float*)d_in[6];
  const float* wn     = (const float*)d_in[7];
  const float* vn     = (const float*)d_in[8];
  float* out = (float*)d_out;

  kA<<<2048, 256, 0, stream>>>(wn, inputs, Fm, Bm, SW, out);
  kB0<<<256, 256, 0, stream>>>(Fm, out);
  kB1<<<64, 256, 0, stream>>>(Fm, state0, out);
  kB2<<<256, 256, 0, stream>>>(Fm, out);
  kC<<<2048, 256, 0, stream>>>(wn, inputs, vn, Fm, Bm, Hm, SW, SV, out);
}

// Round 5
// 766.537 us; speedup vs baseline: 2.4168x; 1.5485x over previous
//
#include <hip/hip_runtime.h>

// Linear SSM group scan, R5 restructure.
// G=2, B=128, L=2048, SD=64, ID=16, OD=16. All fp32, exact decomposition.
//
// Pipeline:
//  kPre : D[l,g,b,:] = SW@wn + B@u  (LDS-tiled GEMM) -> states region of out.
//  kA   : zero-init chunk recurrence, F-only (z(l0)=D[l0] shortcut, 3 steps),
//         writes zend4(c4) into obs-region scratch slot(c4).
//  kBscan: init4(c4+1) = F^4 init4(c4) + zend4(c4), 512-step scan per (g,b);
//         overwrites zend4 slot with init4 in place (same-wave read->write).
//  kC   : true chunk recurrence, F-only + D-add; obs = H@z + SV@vn fused;
//         reads init4 from its own obs slot, then overwrites it with obs;
//         reads D[l] from state slot, overwrites with true state (same-thread
//         read-before-write).
// Rationale (R4 post-mortem): coloring GEMM has no recurrence - hoisting it
// halves the recurrent kernels' MACs AND their wave-uniform scalar stream
// (64 dwords/row fits the SGPR prefetch window; 144 did not).
#define G_ 2
#define B_ 128
#define L_ 2048
#define SD 64
#define ID 16
#define OD 16
#define NC4 512
#define OBS_BASE ((size_t)(G_) * B_ * L_ * SD)

typedef float v2 __attribute__((ext_vector_type(2)));

static __device__ __forceinline__ size_t slotof(int g, int b, int l) {
  return (((size_t)g * B_ + b) * L_ + l) * (size_t)SD;
}
// obs-region scratch slot: 64 floats per (g,b,c4) == obs[g,b,l0..l0+3,:]
static __device__ __forceinline__ size_t oslot(int g, int b, int c4) {
  return OBS_BASE + (((size_t)g * B_ + b) * L_ + (size_t)c4 * 4) * OD;
}
static __device__ __forceinline__ float rl(float v, int lane) {
  return __builtin_bit_cast(float, __builtin_amdgcn_readlane(__builtin_bit_cast(int, v), lane));
}
// LDS-only barrier: order ds ops without draining vmcnt.
static __device__ __forceinline__ void lds_barrier() {
  asm volatile("s_waitcnt lgkmcnt(0)\n\ts_barrier" ::: "memory");
}

// C = A*A (64x64), 256 threads. Caller syncs before and after.
static __device__ void lds_sq(const float* A, float* C, int tid) {
  const int r = tid & 63, q = tid >> 6;
  const float4* Ar = (const float4*)(A + r * SD);
  float acc[16];
#pragma unroll
  for (int c = 0; c < 16; ++c) acc[c] = 0.f;
#pragma unroll 1
  for (int k4 = 0; k4 < 16; ++k4) {
    float4 af = Ar[k4];
    const float* Bb = A + k4 * 4 * SD + q * 16;
#pragma unroll
    for (int kk = 0; kk < 4; ++kk) {
      float a = (kk == 0) ? af.x : (kk == 1) ? af.y : (kk == 2) ? af.z : af.w;
      const float4* Bk = (const float4*)(Bb + kk * SD);
#pragma unroll
      for (int c = 0; c < 4; ++c) {
        float4 bv = Bk[c];
        acc[4 * c + 0] = fmaf(a, bv.x, acc[4 * c + 0]);
        acc[4 * c + 1] = fmaf(a, bv.y, acc[4 * c + 1]);
        acc[4 * c + 2] = fmaf(a, bv.z, acc[4 * c + 2]);
        acc[4 * c + 3] = fmaf(a, bv.w, acc[4 * c + 3]);
      }
    }
  }
  float4* Cr = (float4*)(C + r * SD + q * 16);
#pragma unroll
  for (int c = 0; c < 4; ++c)
    Cr[c] = make_float4(acc[4 * c], acc[4 * c + 1], acc[4 * c + 2], acc[4 * c + 3]);
}

// ---------------------------------------------------------------------------
// kPre: D = SW@wn + B@u for one (g, l, b-half) per block -> state slots.
// LDS-tiled GEMM: Mt[k][row] (matrices transposed), Nt[k][item] (wn/u
// transposed), thread owns 4 rows x 4 items.
// Grid 8192: bid -> g = bid>>12, l = (bid&4095)>>1, b0 = (bid&1)*64.
// ---------------------------------------------------------------------------
__global__ __launch_bounds__(256) void kPre(
    const float* __restrict__ wn, const float* __restrict__ inp,
    const float* __restrict__ SW, const float* __restrict__ Bm,
    float* __restrict__ out) {
  __shared__ __align__(16) float Mt[80 * 64];  // k<64: SW^T, k>=64: B^T
  __shared__ __align__(16) float Nt[80 * 64];  // k<64: wn^T, k>=64: u^T
  const int tid = threadIdx.x;
  const int bid = (int)blockIdx.x;
  const int g = bid >> 12;
  const int rem = bid & 4095;
  const int l = rem >> 1;
  const int b0 = (rem & 1) * 64;
  {
    // SW: thread -> row=tid>>2, k = (tid&3)*16 + 0..15 (coalesced float4)
    const int row = tid >> 2;
    const int k0 = (tid & 3) * 16;
    const float4* sp = (const float4*)(SW + (g * SD + row) * SD + k0);
#pragma unroll
    for (int q = 0; q < 4; ++q) {
      float4 v = sp[q];
      Mt[(k0 + 4 * q + 0) * 64 + row] = v.x;
      Mt[(k0 + 4 * q + 1) * 64 + row] = v.y;
      Mt[(k0 + 4 * q + 2) * 64 + row] = v.z;
      Mt[(k0 + 4 * q + 3) * 64 + row] = v.w;
    }
    // B: row=tid>>2, k2 = (tid&3)*4 + 0..3
    const int k2 = (tid & 3) * 4;
    float4 bv = *(const float4*)(Bm + (g * SD + row) * ID + k2);
    Mt[(64 + k2 + 0) * 64 + row] = bv.x;
    Mt[(64 + k2 + 1) * 64 + row] = bv.y;
    Mt[(64 + k2 + 2) * 64 + row] = bv.z;
    Mt[(64 + k2 + 3) * 64 + row] = bv.w;
  }
  {
    // wn: thread (item=tid&63, kq=tid>>6), k = kq*16 + 0..15
    const int item = tid & 63;
    const int kq = tid >> 6;
    const float4* wp =
        (const float4*)(wn + (((size_t)l * G_ + g) * B_ + b0 + item) * SD + kq * 16);
#pragma unroll
    for (int q = 0; q < 4; ++q) {
      float4 v = wp[q];
      const int k = kq * 16 + 4 * q;
      Nt[(k + 0) * 64 + item] = v.x;
      Nt[(k + 1) * 64 + item] = v.y;
      Nt[(k + 2) * 64 + item] = v.z;
      Nt[(k + 3) * 64 + item] = v.w;
    }
    // u: thread item2=tid>>2, k2 = (tid&3)*4 + 0..3
    const int item2 = tid >> 2;
    const int k2 = (tid & 3) * 4;
    float4 uv = *(const float4*)(inp + (((size_t)g * B_ + b0 + item2) * L_ + l) * ID + k2);
    Nt[(64 + k2 + 0) * 64 + item2] = uv.x;
    Nt[(64 + k2 + 1) * 64 + item2] = uv.y;
    Nt[(64 + k2 + 2) * 64 + item2] = uv.z;
    Nt[(64 + k2 + 3) * 64 + item2] = uv.w;
  }
  __syncthreads();
  const int i0 = (tid & 15) * 4;
  const int r0 = (tid >> 4) * 4;
  float acc[4][4];
#pragma unroll
  for (int r = 0; r < 4; ++r)
#pragma unroll
    for (int i = 0; i < 4; ++i) acc[r][i] = 0.f;
#pragma unroll 4
  for (int k = 0; k < 80; ++k) {
    float4 a = *(const float4*)(Mt + k * 64 + r0);
    float4 w = *(const float4*)(Nt + k * 64 + i0);
    float ar[4] = {a.x, a.y, a.z, a.w};
    float wi[4] = {w.x, w.y, w.z, w.w};
#pragma unroll
    for (int r = 0; r < 4; ++r)
#pragma unroll
      for (int i = 0; i < 4; ++i) acc[r][i] = fmaf(ar[r], wi[i], acc[r][i]);
  }
#pragma unroll
  for (int i = 0; i < 4; ++i) {
    float4 v = make_float4(acc[0][i], acc[1][i], acc[2][i], acc[3][i]);
    *(float4*)(out + slotof(g, b0 + i0 + i, l) + r0) = v;
  }
}

// ---------------------------------------------------------------------------
// kA: zero-init chunk recurrence, F-only. z(l0) = D[l0]; 3 F-steps; writes
// zend4(c4) to obs scratch. Grid 2048: (g, half, c4).
// ---------------------------------------------------------------------------
__global__ __launch_bounds__(256, 2) void kA(const float* __restrict__ Fm,
                                             float* __restrict__ out) {
  __shared__ __align__(16) float zb[SD * 64];  // [comp][item]
  const int tid = threadIdx.x;
  const int bid = (int)blockIdx.x;
  const int c4 = bid & (NC4 - 1);
  const int half = (bid >> 9) & 1;
  const int g = bid >> 10;
  const int l0 = c4 * 4;
  const int lane = tid & 63;
  const int ww = __builtin_amdgcn_readfirstlane(tid >> 6);
  const int b = half * 64 + lane;
  const int row0 = ww * 16;
  const float* __restrict__ Fg = Fm + g * SD * SD;

  v2 z2[32];
  {
    const float4* ip = (const float4*)(out + slotof(g, b, l0));  // D[l0]
#pragma unroll
    for (int q = 0; q < 16; ++q) {
      float4 f = ip[q];
      z2[2 * q] = (v2){f.x, f.y};
      z2[2 * q + 1] = (v2){f.z, f.w};
    }
  }
  float4 d4[4];
  {
    const float4* dp = (const float4*)(out + slotof(g, b, l0 + 1) + row0);
#pragma unroll
    for (int q = 0; q < 4; ++q) d4[q] = dp[q];
  }

#pragma unroll 1
  for (int j = 1; j < 4; ++j) {
    if (j != 1) lds_barrier();  // prev regather drained
#pragma unroll
    for (int c = 0; c < 16; ++c) {
      const int row = row0 + c;
      const float4* fr = (const float4*)(Fg + row * SD);
      v2 a0 = {0.f, 0.f}, a1 = {0.f, 0.f}, a2 = {0.f, 0.f}, a3 = {0.f, 0.f};
#pragma unroll
      for (int q = 0; q < 16; ++q) {
        float4 f = fr[q];
        if (q & 1) {
          a2 += (v2){f.x, f.y} * z2[2 * q];
          a3 += (v2){f.z, f.w} * z2[2 * q + 1];
        } else {
          a0 += (v2){f.x, f.y} * z2[2 * q];
          a1 += (v2){f.z, f.w} * z2[2 * q + 1];
        }
      }
      v2 aa = (a0 + a1) + (a2 + a3);
      float dv = ((c & 3) == 0) ? d4[c >> 2].x
               : ((c & 3) == 1) ? d4[c >> 2].y
               : ((c & 3) == 2) ? d4[c >> 2].z : d4[c >> 2].w;
      zb[row * 64 + lane] = aa.x + aa.y + dv;
    }
    float4 d4n[4];
    if (j != 3) {  // prefetch D[l0+j+1]; in flight across barrier + regather
      const float4* dp = (const float4*)(out + slotof(g, b, l0 + j + 1) + row0);
#pragma unroll
      for (int q = 0; q < 4; ++q) d4n[q] = dp[q];
    }
    lds_barrier();  // zb complete
    if (j != 3) {
#pragma unroll
      for (int k = 0; k < 32; ++k)
        z2[k] = (v2){zb[(2 * k) * 64 + lane], zb[(2 * k + 1) * 64 + lane]};
#pragma unroll
      for (int q = 0; q < 4; ++q) d4[q] = d4n[q];
    }
  }
  // cooperative zend4 store -> obs scratch slot(c4)
  {
    const int item = tid & 63;
    const int kg = tid >> 6;
    float* dst = out + oslot(g, half * 64 + item, c4);
#pragma unroll
    for (int r = 0; r < 4; ++r) {
      float4 v;
      v.x = zb[(kg * 16 + 4 * r + 0) * 64 + item];
      v.y = zb[(kg * 16 + 4 * r + 1) * 64 + item];
      v.z = zb[(kg * 16 + 4 * r + 2) * 64 + item];
      v.w = zb[(kg * 16 + 4 * r + 3) * 64 + item];
      ((float4*)dst)[kg * 4 + r] = v;
    }
  }
}

// ---------------------------------------------------------------------------
// kBscan: init4(c4+1) = F^4 * init4(c4) + zend4(c4), init4(0) = s0.
// One wave per (g,b), lane = state dim; 512 sequential steps; in-place
// zend4 -> init4 slot swap (same-wave load-then-store).
// ---------------------------------------------------------------------------
__global__ __launch_bounds__(256) void kBscan(const float* __restrict__ Fm,
                                              const float* __restrict__ s0,
                                              float* __restrict__ out) {
  __shared__ __align__(16) float bufA[SD * SD];
  __shared__ __align__(16) float bufB[SD * SD];
  const int tid = threadIdx.x;
  const int gb = (int)blockIdx.x * 4 + (tid >> 6);
  const int g = gb >> 7, b = gb & 127;
  const int lane = tid & 63;
  {
    const int gg = ((int)blockIdx.x * 4) >> 7;  // uniform per block
    const float4* Fg = (const float4*)(Fm + gg * SD * SD);
    float4* A4 = (float4*)bufA;
    for (int i = tid; i < SD * SD / 4; i += 256) A4[i] = Fg[i];
  }
  __syncthreads();
  lds_sq(bufA, bufB, tid);  __syncthreads();  // F^2
  lds_sq(bufB, bufA, tid);  __syncthreads();  // F^4 in bufA

  float frow[SD];
  const float4* Fr = (const float4*)(bufA + lane * SD);
#pragma unroll
  for (int i = 0; i < 16; ++i) {
    float4 f = Fr[i];
    frow[4 * i] = f.x; frow[4 * i + 1] = f.y; frow[4 * i + 2] = f.z; frow[4 * i + 3] = f.w;
  }
  float* base = out + oslot(g, b, 0);  // slot(c4) = base + c4*64
  float s = s0[(g * B_ + b) * SD + lane];
  float zcur = base[0 * 64 + lane];
  float znext = base[1 * 64 + lane];
#pragma unroll 1
  for (int c4 = 0; c4 < NC4; ++c4) {
    asm volatile("s_waitcnt vmcnt(0)" ::: "memory");  // zcur/znext/zpf resident
    base[(size_t)c4 * 64 + lane] = s;                 // init4(c4); zend in regs
    const int cn = (c4 + 2 < NC4) ? c4 + 2 : NC4 - 1;
    float zpf = base[(size_t)cn * 64 + lane];
    float a0 = zcur, a1 = 0.f, a2 = 0.f, a3 = 0.f;
#pragma unroll
    for (int k = 0; k < SD; k += 4) {
      a0 = fmaf(frow[k + 0], rl(s, k + 0), a0);
      a1 = fmaf(frow[k + 1], rl(s, k + 1), a1);
      a2 = fmaf(frow[k + 2], rl(s, k + 2), a2);
      a3 = fmaf(frow[k + 3], rl(s, k + 3), a3);
    }
    s = (a0 + a1) + (a2 + a3);
    zcur = znext;
    znext = zpf;
  }
}

// ---------------------------------------------------------------------------
// kC: true chunk recurrence, F-only + D-add; obs = H@z + SV@vn fused.
// Reads init4 from its own obs slot (overwritten later with obs); reads D[l]
// from state slot, overwrites with true state (same-thread read->write).
// ---------------------------------------------------------------------------
__global__ __launch_bounds__(256, 2) void kC(
    const float* __restrict__ vn, const float* __restrict__ Fm,
    const float* __restrict__ Hm, const float* __restrict__ SV,
    float* __restrict__ out) {
  __shared__ __align__(16) float zb[SD * 64];  // [comp][item]
  __shared__ __align__(16) float ob[OD * 64];  // [oc][item]
  const int tid = threadIdx.x;
  const int bid = (int)blockIdx.x;
  const int c4 = bid & (NC4 - 1);
  const int half = (bid >> 9) & 1;
  const int g = bid >> 10;
  const int l0 = c4 * 4;
  const int lane = tid & 63;
  const int ww = __builtin_amdgcn_readfirstlane(tid >> 6);
  const int b = half * 64 + lane;
  const int row0 = ww * 16;
  const int item = tid & 63;
  const int kg = tid >> 6;
  const float* __restrict__ Fg = Fm + g * SD * SD;
  const float* __restrict__ Hg = Hm + g * OD * SD;
  const float* __restrict__ Vg = SV + g * OD * OD;

  v2 z2[32];
  {
    const float4* ip = (const float4*)(out + oslot(g, b, c4));  // init4(c4)
#pragma unroll
    for (int q = 0; q < 16; ++q) {
      float4 f = ip[q];
      z2[2 * q] = (v2){f.x, f.y};
      z2[2 * q + 1] = (v2){f.z, f.w};
    }
  }
  float4 d4[4];
  v2 vv2[8];
  {
    const float4* dp = (const float4*)(out + slotof(g, b, l0) + row0);  // D[l0]
#pragma unroll
    for (int q = 0; q < 4; ++q) d4[q] = dp[q];
    const v2* vp = (const v2*)(vn + (((size_t)l0 * G_ + g) * B_ + b) * OD);
#pragma unroll
    for (int q = 0; q < 8; ++q) vv2[q] = vp[q];
  }

#pragma unroll 1
  for (int j = 0; j < 4; ++j) {
    const int l = l0 + j;
    // zb writes: prior readers drained by barrier C of previous iteration.
#pragma unroll
    for (int c = 0; c < 16; ++c) {
      const int row = row0 + c;
      const float4* fr = (const float4*)(Fg + row * SD);
      v2 a0 = {0.f, 0.f}, a1 = {0.f, 0.f}, a2 = {0.f, 0.f}, a3 = {0.f, 0.f};
#pragma unroll
      for (int q = 0; q < 16; ++q) {
        float4 f = fr[q];
        if (q & 1) {
          a2 += (v2){f.x, f.y} * z2[2 * q];
          a3 += (v2){f.z, f.w} * z2[2 * q + 1];
        } else {
          a0 += (v2){f.x, f.y} * z2[2 * q];
          a1 += (v2){f.z, f.w} * z2[2 * q + 1];
        }
      }
      v2 aa = (a0 + a1) + (a2 + a3);
      float dv = ((c & 3) == 0) ? d4[c >> 2].x
               : ((c & 3) == 1) ? d4[c >> 2].y
               : ((c & 3) == 2) ? d4[c >> 2].z : d4[c >> 2].w;
      zb[row * 64 + lane] = aa.x + aa.y + dv;
    }
    // prefetch next-step D rows + vn; in flight across barrier + store + obs
    float4 d4n[4];
    v2 vvn[8];
    if (j != 3) {
      const float4* dp = (const float4*)(out + slotof(g, b, l + 1) + row0);
#pragma unroll
      for (int q = 0; q < 4; ++q) d4n[q] = dp[q];
      const v2* vp = (const v2*)(vn + (((size_t)(l + 1) * G_ + g) * B_ + b) * OD);
#pragma unroll
      for (int q = 0; q < 8; ++q) vvn[q] = vp[q];
    }
    lds_barrier();  // B: zb = state(l) complete
    // cooperative state store (overwrites D[l]; this thread already read its
    // own 64 B of D[l] as d4 before this point)
    {
      float* dst = out + slotof(g, half * 64 + item, l);
#pragma unroll
      for (int r = 0; r < 4; ++r) {
        float4 v;
        v.x = zb[(kg * 16 + 4 * r + 0) * 64 + item];
        v.y = zb[(kg * 16 + 4 * r + 1) * 64 + item];
        v.z = zb[(kg * 16 + 4 * r + 2) * 64 + item];
        v.w = zb[(kg * 16 + 4 * r + 3) * 64 + item];
        ((float4*)dst)[kg * 4 + r] = v;
      }
    }
    // regather full state(l) (feeds next step + obs)
#pragma unroll
    for (int k = 0; k < 32; ++k)
      z2[k] = (v2){zb[(2 * k) * 64 + lane], zb[(2 * k + 1) * 64 + lane]};
    // observations: wave ww computes obs rows [4ww, 4ww+4)
#pragma unroll
    for (int oc = 0; oc < 4; ++oc) {
      const int orow = ww * 4 + oc;
      const float4* hr = (const float4*)(Hg + orow * SD);
      const float4* vr = (const float4*)(Vg + orow * OD);
      v2 a0 = {0.f, 0.f}, a1 = {0.f, 0.f};
#pragma unroll
      for (int q = 0; q < 16; ++q) {
        float4 h = hr[q];
        a0 += (v2){h.x, h.y} * z2[2 * q];
        a1 += (v2){h.z, h.w} * z2[2 * q + 1];
      }
#pragma unroll
      for (int q = 0; q < 4; ++q) {
        float4 sv = vr[q];
        a0 += (v2){sv.x, sv.y} * vv2[2 * q];
        a1 += (v2){sv.z, sv.w} * vv2[2 * q + 1];
      }
      v2 aa = a0 + a1;
      ob[orow * 64 + lane] = aa.x + aa.y;
    }
    lds_barrier();  // C: ob complete (orders zb reads before next write)
    // cooperative obs store (overwrites this block's init4 scratch - safe:
    // all lanes consumed init4 before the first barrier)
    {
      float4 v;
      v.x = ob[(4 * kg + 0) * 64 + item];
      v.y = ob[(4 * kg + 1) * 64 + item];
      v.z = ob[(4 * kg + 2) * 64 + item];
      v.w = ob[(4 * kg + 3) * 64 + item];
      float* od = out + OBS_BASE +
                  (((size_t)g * B_ + (half * 64 + item)) * L_ + l) * OD;
      ((float4*)od)[kg] = v;
    }
    if (j != 3) {
#pragma unroll
      for (int q = 0; q < 4; ++q) d4[q] = d4n[q];
#pragma unroll
      for (int q = 0; q < 8; ++q) vv2[q] = vvn[q];
    }
  }
}

extern "C" void kernel_launch(void* const* d_in, const int* in_sizes, int n_in,
                              void* d_out, int out_size, void* d_ws, size_t ws_size,
                              hipStream_t stream) {
  (void)in_sizes; (void)n_in; (void)out_size; (void)d_ws; (void)ws_size;
  const float* state0 = (const float*)d_in[0];
  const float* inputs = (const float*)d_in[1];
  const float* Fm     = (const float*)d_in[2];
  const float* Bm     = (const float*)d_in[3];
  const float* Hm     = (const float*)d_in[4];
  const float* SW     = (const float*)d_in[5];
  const float* SV     = (const float*)d_in[6];
  const float* wn     = (const float*)d_in[7];
  const float* vn     = (const float*)d_in[8];
  float* out = (float*)d_out;

  kPre<<<8192, 256, 0, stream>>>(wn, inputs, SW, Bm, out);
  kA<<<2048, 256, 0, stream>>>(Fm, out);
  kBscan<<<64, 256, 0, stream>>>(Fm, state0, out);
  kC<<<2048, 256, 0, stream>>>(vn, Fm, Hm, SV, out);
}

// Round 6
// 657.399 us; speedup vs baseline: 2.8181x; 1.1660x over previous
//
#include <hip/hip_runtime.h>

// Linear SSM group scan, R6: 3-phase parallel chunk-scan replaces serial kBscan.
// G=2, B=128, L=2048, SD=64, ID=16, OD=16. All fp32, exact decomposition.
//
// Pipeline:
//  kPre  : D[l,g,b,:] = SW@wn + B@u  (LDS-tiled GEMM) -> states region of out.
//  kA    : zero-init chunk recurrence, F-only (z(l0)=D[l0], 3 steps), writes
//          zend4(c4) into obs-region scratch slot(c4).
//  kBscan2: init4 scan, 3-phase: block = (g,b), 1024 thr, 16 waves.
//          wave m owns chunks 32m..32m+31.
//          ph1: carry C(m) = scan-from-zero over 32 chunks (no stores).
//          ph2: wave 0: G(m+1) = F^128 G(m) + C(m), G(0)=s0 (LDS carries).
//          ph3: re-scan from G(m), storing init4(c) in place of zend4(c).
//          F^4 rows in VGPRs (pk_fma + readlane-pair); F^128 via 7 padded
//          LDS squarings (stride 68 kills the 16-way bank conflict).
//  kC    : true chunk recurrence, F-only + D-add; obs = H@z + SV@vn fused.
#define G_ 2
#define B_ 128
#define L_ 2048
#define SD 64
#define ID 16
#define OD 16
#define NC4 512
#define ROWP 68  // padded LDS row stride (dwords) for 64x64 matrices
#define OBS_BASE ((size_t)(G_) * B_ * L_ * SD)

typedef float v2 __attribute__((ext_vector_type(2)));

static __device__ __forceinline__ size_t slotof(int g, int b, int l) {
  return (((size_t)g * B_ + b) * L_ + l) * (size_t)SD;
}
// obs-region scratch slot: 64 floats per (g,b,c4) == obs[g,b,l0..l0+3,:]
static __device__ __forceinline__ size_t oslot(int g, int b, int c4) {
  return OBS_BASE + (((size_t)g * B_ + b) * L_ + (size_t)c4 * 4) * OD;
}
static __device__ __forceinline__ float rl(float v, int lane) {
  return __builtin_bit_cast(float, __builtin_amdgcn_readlane(__builtin_bit_cast(int, v), lane));
}
// acc += m * z, packed fp32; m wave-uniform (SGPR pair), z per-lane (VGPRs).
static __device__ __forceinline__ void pkfma_s(v2& acc, v2 m, v2 z) {
  asm("v_pk_fma_f32 %0, %1, %2, %0" : "+v"(acc) : "s"(m), "v"(z));
}
// LDS-only barrier: order ds ops without draining vmcnt.
static __device__ __forceinline__ void lds_barrier() {
  asm volatile("s_waitcnt lgkmcnt(0)\n\ts_barrier" ::: "memory");
}

// s' = A*s + add, lane = component. A rows (row=lane) in fr2 (32 v2 regs).
// 64 readlane broadcasts (pairs into SGPR) + 32 pk_fma.
static __device__ __forceinline__ float a_step(const v2 (&fr2)[32], float s, float add) {
  v2 a0 = {add, 0.f}, a1 = {0.f, 0.f}, a2 = {0.f, 0.f}, a3 = {0.f, 0.f};
#pragma unroll
  for (int k2 = 0; k2 < 32; ++k2) {
    v2 m;
    m.x = rl(s, 2 * k2);
    m.y = rl(s, 2 * k2 + 1);
    if ((k2 & 3) == 0)      pkfma_s(a0, m, fr2[k2]);
    else if ((k2 & 3) == 1) pkfma_s(a1, m, fr2[k2]);
    else if ((k2 & 3) == 2) pkfma_s(a2, m, fr2[k2]);
    else                    pkfma_s(a3, m, fr2[k2]);
  }
  v2 aa = (a0 + a1) + (a2 + a3);
  return aa.x + aa.y;
}

// C = A*A (64x64, ROWP-padded LDS), 256 threads (waves 0-3 of the block).
// Caller syncs before and after.
static __device__ void lds_sq_p(const float* A, float* C, int tid) {
  const int r = tid & 63, q = tid >> 6;  // q in 0..3, uniform per wave
  const float4* Ar = (const float4*)(A + r * ROWP);
  float acc[16];
#pragma unroll
  for (int c = 0; c < 16; ++c) acc[c] = 0.f;
#pragma unroll 1
  for (int k4 = 0; k4 < 16; ++k4) {
    float4 af = Ar[k4];
#pragma unroll
    for (int kk = 0; kk < 4; ++kk) {
      float a = (kk == 0) ? af.x : (kk == 1) ? af.y : (kk == 2) ? af.z : af.w;
      const float4* Bk = (const float4*)(A + (k4 * 4 + kk) * ROWP + q * 16);
#pragma unroll
      for (int c = 0; c < 4; ++c) {
        float4 bv = Bk[c];
        acc[4 * c + 0] = fmaf(a, bv.x, acc[4 * c + 0]);
        acc[4 * c + 1] = fmaf(a, bv.y, acc[4 * c + 1]);
        acc[4 * c + 2] = fmaf(a, bv.z, acc[4 * c + 2]);
        acc[4 * c + 3] = fmaf(a, bv.w, acc[4 * c + 3]);
      }
    }
  }
  float4* Cr = (float4*)(C + r * ROWP + q * 16);
#pragma unroll
  for (int c = 0; c < 4; ++c)
    Cr[c] = make_float4(acc[4 * c], acc[4 * c + 1], acc[4 * c + 2], acc[4 * c + 3]);
}

// ---------------------------------------------------------------------------
// kPre: D = SW@wn + B@u for one (g, l, b-half) per block -> state slots.
// ---------------------------------------------------------------------------
__global__ __launch_bounds__(256) void kPre(
    const float* __restrict__ wn, const float* __restrict__ inp,
    const float* __restrict__ SW, const float* __restrict__ Bm,
    float* __restrict__ out) {
  __shared__ __align__(16) float Mt[80 * 64];  // k<64: SW^T, k>=64: B^T
  __shared__ __align__(16) float Nt[80 * 64];  // k<64: wn^T, k>=64: u^T
  const int tid = threadIdx.x;
  const int bid = (int)blockIdx.x;
  const int g = bid >> 12;
  const int rem = bid & 4095;
  const int l = rem >> 1;
  const int b0 = (rem & 1) * 64;
  {
    const int row = tid >> 2;
    const int k0 = (tid & 3) * 16;
    const float4* sp = (const float4*)(SW + (g * SD + row) * SD + k0);
#pragma unroll
    for (int q = 0; q < 4; ++q) {
      float4 v = sp[q];
      Mt[(k0 + 4 * q + 0) * 64 + row] = v.x;
      Mt[(k0 + 4 * q + 1) * 64 + row] = v.y;
      Mt[(k0 + 4 * q + 2) * 64 + row] = v.z;
      Mt[(k0 + 4 * q + 3) * 64 + row] = v.w;
    }
    const int k2 = (tid & 3) * 4;
    float4 bv = *(const float4*)(Bm + (g * SD + row) * ID + k2);
    Mt[(64 + k2 + 0) * 64 + row] = bv.x;
    Mt[(64 + k2 + 1) * 64 + row] = bv.y;
    Mt[(64 + k2 + 2) * 64 + row] = bv.z;
    Mt[(64 + k2 + 3) * 64 + row] = bv.w;
  }
  {
    const int item = tid & 63;
    const int kq = tid >> 6;
    const float4* wp =
        (const float4*)(wn + (((size_t)l * G_ + g) * B_ + b0 + item) * SD + kq * 16);
#pragma unroll
    for (int q = 0; q < 4; ++q) {
      float4 v = wp[q];
      const int k = kq * 16 + 4 * q;
      Nt[(k + 0) * 64 + item] = v.x;
      Nt[(k + 1) * 64 + item] = v.y;
      Nt[(k + 2) * 64 + item] = v.z;
      Nt[(k + 3) * 64 + item] = v.w;
    }
    const int item2 = tid >> 2;
    const int k2 = (tid & 3) * 4;
    float4 uv = *(const float4*)(inp + (((size_t)g * B_ + b0 + item2) * L_ + l) * ID + k2);
    Nt[(64 + k2 + 0) * 64 + item2] = uv.x;
    Nt[(64 + k2 + 1) * 64 + item2] = uv.y;
    Nt[(64 + k2 + 2) * 64 + item2] = uv.z;
    Nt[(64 + k2 + 3) * 64 + item2] = uv.w;
  }
  __syncthreads();
  const int i0 = (tid & 15) * 4;
  const int r0 = (tid >> 4) * 4;
  float acc[4][4];
#pragma unroll
  for (int r = 0; r < 4; ++r)
#pragma unroll
    for (int i = 0; i < 4; ++i) acc[r][i] = 0.f;
#pragma unroll 4
  for (int k = 0; k < 80; ++k) {
    float4 a = *(const float4*)(Mt + k * 64 + r0);
    float4 w = *(const float4*)(Nt + k * 64 + i0);
    float ar[4] = {a.x, a.y, a.z, a.w};
    float wi[4] = {w.x, w.y, w.z, w.w};
#pragma unroll
    for (int r = 0; r < 4; ++r)
#pragma unroll
      for (int i = 0; i < 4; ++i) acc[r][i] = fmaf(ar[r], wi[i], acc[r][i]);
  }
#pragma unroll
  for (int i = 0; i < 4; ++i) {
    float4 v = make_float4(acc[0][i], acc[1][i], acc[2][i], acc[3][i]);
    *(float4*)(out + slotof(g, b0 + i0 + i, l) + r0) = v;
  }
}

// ---------------------------------------------------------------------------
// kA: zero-init chunk recurrence, F-only. z(l0) = D[l0]; 3 F-steps; writes
// zend4(c4) to obs scratch. Grid 2048: (g, half, c4).
// ---------------------------------------------------------------------------
__global__ __launch_bounds__(256, 2) void kA(const float* __restrict__ Fm,
                                             float* __restrict__ out) {
  __shared__ __align__(16) float zb[SD * 64];  // [comp][item]
  const int tid = threadIdx.x;
  const int bid = (int)blockIdx.x;
  const int c4 = bid & (NC4 - 1);
  const int half = (bid >> 9) & 1;
  const int g = bid >> 10;
  const int l0 = c4 * 4;
  const int lane = tid & 63;
  const int ww = __builtin_amdgcn_readfirstlane(tid >> 6);
  const int b = half * 64 + lane;
  const int row0 = ww * 16;
  const float* __restrict__ Fg = Fm + g * SD * SD;

  v2 z2[32];
  {
    const float4* ip = (const float4*)(out + slotof(g, b, l0));  // D[l0]
#pragma unroll
    for (int q = 0; q < 16; ++q) {
      float4 f = ip[q];
      z2[2 * q] = (v2){f.x, f.y};
      z2[2 * q + 1] = (v2){f.z, f.w};
    }
  }
  float4 d4[4];
  {
    const float4* dp = (const float4*)(out + slotof(g, b, l0 + 1) + row0);
#pragma unroll
    for (int q = 0; q < 4; ++q) d4[q] = dp[q];
  }

#pragma unroll 1
  for (int j = 1; j < 4; ++j) {
    if (j != 1) lds_barrier();  // prev regather drained
#pragma unroll
    for (int c = 0; c < 16; ++c) {
      const int row = row0 + c;
      const float4* fr = (const float4*)(Fg + row * SD);
      v2 a0 = {0.f, 0.f}, a1 = {0.f, 0.f}, a2 = {0.f, 0.f}, a3 = {0.f, 0.f};
#pragma unroll
      for (int q = 0; q < 16; ++q) {
        float4 f = fr[q];
        if (q & 1) {
          a2 += (v2){f.x, f.y} * z2[2 * q];
          a3 += (v2){f.z, f.w} * z2[2 * q + 1];
        } else {
          a0 += (v2){f.x, f.y} * z2[2 * q];
          a1 += (v2){f.z, f.w} * z2[2 * q + 1];
        }
      }
      v2 aa = (a0 + a1) + (a2 + a3);
      float dv = ((c & 3) == 0) ? d4[c >> 2].x
               : ((c & 3) == 1) ? d4[c >> 2].y
               : ((c & 3) == 2) ? d4[c >> 2].z : d4[c >> 2].w;
      zb[row * 64 + lane] = aa.x + aa.y + dv;
    }
    float4 d4n[4];
    if (j != 3) {  // prefetch D[l0+j+1]; in flight across barrier + regather
      const float4* dp = (const float4*)(out + slotof(g, b, l0 + j + 1) + row0);
#pragma unroll
      for (int q = 0; q < 4; ++q) d4n[q] = dp[q];
    }
    lds_barrier();  // zb complete
    if (j != 3) {
#pragma unroll
      for (int k = 0; k < 32; ++k)
        z2[k] = (v2){zb[(2 * k) * 64 + lane], zb[(2 * k + 1) * 64 + lane]};
#pragma unroll
      for (int q = 0; q < 4; ++q) d4[q] = d4n[q];
    }
  }
  // cooperative zend4 store -> obs scratch slot(c4)
  {
    const int item = tid & 63;
    const int kg = tid >> 6;
    float* dst = out + oslot(g, half * 64 + item, c4);
#pragma unroll
    for (int r = 0; r < 4; ++r) {
      float4 v;
      v.x = zb[(kg * 16 + 4 * r + 0) * 64 + item];
      v.y = zb[(kg * 16 + 4 * r + 1) * 64 + item];
      v.z = zb[(kg * 16 + 4 * r + 2) * 64 + item];
      v.w = zb[(kg * 16 + 4 * r + 3) * 64 + item];
      ((float4*)dst)[kg * 4 + r] = v;
    }
  }
}

// ---------------------------------------------------------------------------
// kBscan2: 3-phase init4 scan. Block = (g,b), 1024 threads, 16 waves.
// A = F^4. Recurrence: init(c+1) = A init(c) + z(c), init(0) = s0.
// Wave m owns chunks [32m, 32m+32). zend z(c) at base + c*64; overwritten
// in place by init(c) during phase 3.
// ---------------------------------------------------------------------------
__global__ __launch_bounds__(1024, 4) void kBscan2(const float* __restrict__ Fm,
                                                   const float* __restrict__ s0,
                                                   float* __restrict__ out) {
  __shared__ __align__(16) float bufA[SD * ROWP];  // 17.4 KB
  __shared__ __align__(16) float bufB[SD * ROWP];  // 17.4 KB
  __shared__ float carr[16][64];
  __shared__ float gbuf[16][64];
  const int tid = threadIdx.x;
  const int bid = (int)blockIdx.x;
  const int g = bid >> 7;
  const int b = bid & 127;
  const int lane = tid & 63;
  const int w = __builtin_amdgcn_readfirstlane(tid >> 6);  // wave = group m

  // load F into padded bufA
  {
    const float* Fg = Fm + g * SD * SD;
    for (int i = tid; i < SD * SD; i += 1024)
      bufA[(i >> 6) * ROWP + (i & 63)] = Fg[i];
  }
  __syncthreads();
  // squaring chain (waves 0-3 compute; all sync):
  // A->B:F2, B->A:F4 [extract rows], A->B:F8, B->A:F16, A->B:F32, B->A:F64,
  // A->B:F128.
  if (tid < 256) lds_sq_p(bufA, bufB, tid);
  __syncthreads();
  if (tid < 256) lds_sq_p(bufB, bufA, tid);
  __syncthreads();
  v2 fr2[32];  // row `lane` of F^4
  {
    const v2* rp = (const v2*)(bufA + lane * ROWP);
#pragma unroll
    for (int k = 0; k < 32; ++k) fr2[k] = rp[k];
  }
  __syncthreads();  // everyone has fr2 before bufA is overwritten
  if (tid < 256) lds_sq_p(bufA, bufB, tid);
  __syncthreads();
  if (tid < 256) lds_sq_p(bufB, bufA, tid);
  __syncthreads();
  if (tid < 256) lds_sq_p(bufA, bufB, tid);
  __syncthreads();
  if (tid < 256) lds_sq_p(bufB, bufA, tid);
  __syncthreads();
  if (tid < 256) lds_sq_p(bufA, bufB, tid);  // F^128 in bufB
  __syncthreads();

  float* base = out + oslot(g, b, 0);  // z(c) / init(c) at base + c*64
  const int c0 = w * 32;

  // phase 1: carry C(m) = scan-from-zero over the group's 32 chunks.
  {
    float s = 0.f;
    float z0 = base[(size_t)c0 * 64 + lane];
    float z1 = base[(size_t)(c0 + 1) * 64 + lane];
#pragma unroll 1
    for (int i = 0; i < 32; ++i) {
      const int cn = (i + 2 < 32) ? c0 + i + 2 : c0 + 31;
      float zpf = base[(size_t)cn * 64 + lane];
      s = a_step(fr2, s, z0);
      z0 = z1;
      z1 = zpf;
    }
    carr[w][lane] = s;
  }
  __syncthreads();
  // phase 2: wave 0: G(0)=s0; G(m+1) = F^128 G(m) + C(m). A128 rows from LDS.
  if (w == 0) {
    const float* arow = bufB + lane * ROWP;  // row `lane` of F^128
    float G = s0[(g * B_ + b) * SD + lane];
#pragma unroll 1
    for (int m = 0; m < 16; ++m) {
      gbuf[m][lane] = G;
      v2 a0 = {carr[m][lane], 0.f}, a1 = {0.f, 0.f}, a2 = {0.f, 0.f}, a3 = {0.f, 0.f};
#pragma unroll
      for (int k2 = 0; k2 < 32; ++k2) {
        v2 mr = ((const v2*)arow)[k2];
        v2 mm;
        mm.x = rl(G, 2 * k2);
        mm.y = rl(G, 2 * k2 + 1);
        if ((k2 & 3) == 0)      pkfma_s(a0, mm, mr);
        else if ((k2 & 3) == 1) pkfma_s(a1, mm, mr);
        else if ((k2 & 3) == 2) pkfma_s(a2, mm, mr);
        else                    pkfma_s(a3, mm, mr);
      }
      v2 aa = (a0 + a1) + (a2 + a3);
      G = aa.x + aa.y;
    }
  }
  __syncthreads();
  // phase 3: re-scan from true init G(m); store init(c) over z(c) in place.
  {
    float s = gbuf[w][lane];
    float zcur = base[(size_t)c0 * 64 + lane];
    float znext = base[(size_t)(c0 + 1) * 64 + lane];
#pragma unroll 1
    for (int i = 0; i < 32; ++i) {
      const int c = c0 + i;
      asm volatile("s_waitcnt vmcnt(0)" ::: "memory");  // zcur/znext resident
      base[(size_t)c * 64 + lane] = s;                  // init(c)
      const int cn = (i + 2 < 32) ? c + 2 : c0 + 31;    // dead load at tail
      float zpf = base[(size_t)cn * 64 + lane];
      s = a_step(fr2, s, zcur);
      zcur = znext;
      znext = zpf;
    }
  }
}

// ---------------------------------------------------------------------------
// kC: true chunk recurrence, F-only + D-add; obs = H@z + SV@vn fused.
// ---------------------------------------------------------------------------
__global__ __launch_bounds__(256, 2) void kC(
    const float* __restrict__ vn, const float* __restrict__ Fm,
    const float* __restrict__ Hm, const float* __restrict__ SV,
    float* __restrict__ out) {
  __shared__ __align__(16) float zb[SD * 64];  // [comp][item]
  __shared__ __align__(16) float ob[OD * 64];  // [oc][item]
  const int tid = threadIdx.x;
  const int bid = (int)blockIdx.x;
  const int c4 = bid & (NC4 - 1);
  const int half = (bid >> 9) & 1;
  const int g = bid >> 10;
  const int l0 = c4 * 4;
  const int lane = tid & 63;
  const int ww = __builtin_amdgcn_readfirstlane(tid >> 6);
  const int b = half * 64 + lane;
  const int row0 = ww * 16;
  const int item = tid & 63;
  const int kg = tid >> 6;
  const float* __restrict__ Fg = Fm + g * SD * SD;
  const float* __restrict__ Hg = Hm + g * OD * SD;
  const float* __restrict__ Vg = SV + g * OD * OD;

  v2 z2[32];
  {
    const float4* ip = (const float4*)(out + oslot(g, b, c4));  // init4(c4)
#pragma unroll
    for (int q = 0; q < 16; ++q) {
      float4 f = ip[q];
      z2[2 * q] = (v2){f.x, f.y};
      z2[2 * q + 1] = (v2){f.z, f.w};
    }
  }
  float4 d4[4];
  v2 vv2[8];
  {
    const float4* dp = (const float4*)(out + slotof(g, b, l0) + row0);  // D[l0]
#pragma unroll
    for (int q = 0; q < 4; ++q) d4[q] = dp[q];
    const v2* vp = (const v2*)(vn + (((size_t)l0 * G_ + g) * B_ + b) * OD);
#pragma unroll
    for (int q = 0; q < 8; ++q) vv2[q] = vp[q];
  }

#pragma unroll 1
  for (int j = 0; j < 4; ++j) {
    const int l = l0 + j;
#pragma unroll
    for (int c = 0; c < 16; ++c) {
      const int row = row0 + c;
      const float4* fr = (const float4*)(Fg + row * SD);
      v2 a0 = {0.f, 0.f}, a1 = {0.f, 0.f}, a2 = {0.f, 0.f}, a3 = {0.f, 0.f};
#pragma unroll
      for (int q = 0; q < 16; ++q) {
        float4 f = fr[q];
        if (q & 1) {
          a2 += (v2){f.x, f.y} * z2[2 * q];
          a3 += (v2){f.z, f.w} * z2[2 * q + 1];
        } else {
          a0 += (v2){f.x, f.y} * z2[2 * q];
          a1 += (v2){f.z, f.w} * z2[2 * q + 1];
        }
      }
      v2 aa = (a0 + a1) + (a2 + a3);
      float dv = ((c & 3) == 0) ? d4[c >> 2].x
               : ((c & 3) == 1) ? d4[c >> 2].y
               : ((c & 3) == 2) ? d4[c >> 2].z : d4[c >> 2].w;
      zb[row * 64 + lane] = aa.x + aa.y + dv;
    }
    float4 d4n[4];
    v2 vvn[8];
    if (j != 3) {
      const float4* dp = (const float4*)(out + slotof(g, b, l + 1) + row0);
#pragma unroll
      for (int q = 0; q < 4; ++q) d4n[q] = dp[q];
      const v2* vp = (const v2*)(vn + (((size_t)(l + 1) * G_ + g) * B_ + b) * OD);
#pragma unroll
      for (int q = 0; q < 8; ++q) vvn[q] = vp[q];
    }
    lds_barrier();  // B: zb = state(l) complete
    {
      float* dst = out + slotof(g, half * 64 + item, l);
#pragma unroll
      for (int r = 0; r < 4; ++r) {
        float4 v;
        v.x = zb[(kg * 16 + 4 * r + 0) * 64 + item];
        v.y = zb[(kg * 16 + 4 * r + 1) * 64 + item];
        v.z = zb[(kg * 16 + 4 * r + 2) * 64 + item];
        v.w = zb[(kg * 16 + 4 * r + 3) * 64 + item];
        ((float4*)dst)[kg * 4 + r] = v;
      }
    }
#pragma unroll
    for (int k = 0; k < 32; ++k)
      z2[k] = (v2){zb[(2 * k) * 64 + lane], zb[(2 * k + 1) * 64 + lane]};
#pragma unroll
    for (int oc = 0; oc < 4; ++oc) {
      const int orow = ww * 4 + oc;
      const float4* hr = (const float4*)(Hg + orow * SD);
      const float4* vr = (const float4*)(Vg + orow * OD);
      v2 a0 = {0.f, 0.f}, a1 = {0.f, 0.f};
#pragma unroll
      for (int q = 0; q < 16; ++q) {
        float4 h = hr[q];
        a0 += (v2){h.x, h.y} * z2[2 * q];
        a1 += (v2){h.z, h.w} * z2[2 * q + 1];
      }
#pragma unroll
      for (int q = 0; q < 4; ++q) {
        float4 sv = vr[q];
        a0 += (v2){sv.x, sv.y} * vv2[2 * q];
        a1 += (v2){sv.z, sv.w} * vv2[2 * q + 1];
      }
      v2 aa = a0 + a1;
      ob[orow * 64 + lane] = aa.x + aa.y;
    }
    lds_barrier();  // C: ob complete (orders zb reads before next write)
    {
      float4 v;
      v.x = ob[(4 * kg + 0) * 64 + item];
      v.y = ob[(4 * kg + 1) * 64 + item];
      v.z = ob[(4 * kg + 2) * 64 + item];
      v.w = ob[(4 * kg + 3) * 64 + item];
      float* od = out + OBS_BASE +
                  (((size_t)g * B_ + (half * 64 + item)) * L_ + l) * OD;
      ((float4*)od)[kg] = v;
    }
    if (j != 3) {
#pragma unroll
      for (int q = 0; q < 4; ++q) d4[q] = d4n[q];
#pragma unroll
      for (int q = 0; q < 8; ++q) vv2[q] = vvn[q];
    }
  }
}

extern "C" void kernel_launch(void* const* d_in, const int* in_sizes, int n_in,
                              void* d_out, int out_size, void* d_ws, size_t ws_size,
                              hipStream_t stream) {
  (void)in_sizes; (void)n_in; (void)out_size; (void)d_ws; (void)ws_size;
  const float* state0 = (const float*)d_in[0];
  const float* inputs = (const float*)d_in[1];
  const float* Fm     = (const float*)d_in[2];
  const float* Bm     = (const float*)d_in[3];
  const float* Hm     = (const float*)d_in[4];
  const float* SW     = (const float*)d_in[5];
  const float* SV     = (const float*)d_in[6];
  const float* wn     = (const float*)d_in[7];
  const float* vn     = (const float*)d_in[8];
  float* out = (float*)d_out;

  kPre<<<8192, 256, 0, stream>>>(wn, inputs, SW, Bm, out);
  kA<<<2048, 256, 0, stream>>>(Fm, out);
  kBscan2<<<256, 1024, 0, stream>>>(Fm, state0, out);
  kC<<<2048, 256, 0, stream>>>(vn, Fm, Hm, SV, out);
}